// Round 19
// baseline (716.669 us; speedup 1.0000x reference)
//
#include <hip/hip_runtime.h>

// ---------------------------------------------------------------------------
// SparseGRUBrain: N=70000, H=8, E=1.12M, B=8.
// R19: structural rewrite -- NO CSR, NO records. Three dispatches:
//   P1 zero_calt: zeros inp[3][N][B][H] accumulators + builds calT (N x 8).
//   P2 edge_atomic: one WAVE per edge (lane = b*8+h); computes W[e,h]*cal[b,src]
//      for all 64 (b,h) and 3 gates; scatters via 3 wave-level atomicAdd
//      instructions, each 64 consecutive f32 (256B) at inp[gate][tgt].
//   P3 gru_dense: pure dense per (n,b): inp + U*h einsums + gates + proj.
// All fp32 (absmax control: should drop to ~1e-4 from 0.03125).
// Workspace (bytes):
//   [0,     2.24M)  calT (N x 8 f32)
//   [4M,    +53.8M) inp  (3 gates x N x 64 f32, contiguous: Z, R, H)
// ---------------------------------------------------------------------------

typedef float f2 __attribute__((ext_vector_type(2)));

__device__ __forceinline__ float fast_sigmoid(float x) {
    return 1.0f / (1.0f + __expf(-x));
}
__device__ __forceinline__ float fast_tanh(float x) {
    return 2.0f / (1.0f + __expf(-2.0f * x)) - 1.0f;
}

// P1: zero the 3 gate accumulators (float4 grid-stride) + calT transpose.
__global__ __launch_bounds__(256) void zero_calt(float4* __restrict__ inp4,
                                                 int total4,
                                                 const float* __restrict__ cal,
                                                 float* __restrict__ calT, int N) {
    const int tid = blockIdx.x * 256 + threadIdx.x;
    const int stride = gridDim.x * 256;
    const float4 z4 = make_float4(0.f, 0.f, 0.f, 0.f);
    for (int i = tid; i < total4; i += stride) inp4[i] = z4;
    for (int n = tid; n < N; n += stride) {
        float v[8];
#pragma unroll
        for (int b = 0; b < 8; ++b) v[b] = cal[(size_t)b * N + n];
        float4* o = (float4*)(calT + (size_t)n * 8);
        o[0] = make_float4(v[0], v[1], v[2], v[3]);
        o[1] = make_float4(v[4], v[5], v[6], v[7]);
    }
}

// P2: one wave per 4 edges (sequential loop, independent iterations).
// lane = b*8 + h. Per edge: wz/wr/wh = W*[e][h] (32B broadcast line),
// c = calT[src*8+b] (one 32B line), 3 atomicAdds at inp[gate][tgt*64+lane]
// (64 consecutive f32 per instruction -> 4-line RMW, no partial sectors).
__global__ __launch_bounds__(256) void edge_atomic(
    const int* __restrict__ src, const int* __restrict__ tgt,
    const float* __restrict__ Wz, const float* __restrict__ Wr,
    const float* __restrict__ Wh, const float* __restrict__ calT,
    float* __restrict__ inpZ, float* __restrict__ inpR,
    float* __restrict__ inpH, int E) {
    const int lane = threadIdx.x & 63;
    const int wv = (blockIdx.x * 256 + threadIdx.x) >> 6;
    const int b = lane >> 3;
    const int h = lane & 7;
    const int e0 = wv * 4;
#pragma unroll
    for (int k = 0; k < 4; ++k) {
        const int e = e0 + k;
        if (e < E) {
            const int sv = src[e];   // wave-uniform -> scalar load
            const int tv = tgt[e];
            const float wz = Wz[(size_t)e * 8 + h];
            const float wr = Wr[(size_t)e * 8 + h];
            const float wh = Wh[(size_t)e * 8 + h];
            const float c = calT[(size_t)sv * 8 + b];
            const size_t o = (size_t)tv * 64 + lane;
            atomicAdd(&inpZ[o], wz * c);
            atomicAdd(&inpR[o], wr * c);
            atomicAdd(&inpH[o], wh * c);
        }
    }
}

// P3: pure dense GRU. Thread = (n, b); lane group of 8 shares neuron n
// (U/bias loads broadcast), reads its 32B inp/hidden slices, no shuffles.
__global__ __launch_bounds__(256) void gru_dense(
    const float* __restrict__ inpZ, const float* __restrict__ inpR,
    const float* __restrict__ inpH, const float* __restrict__ hidden,
    const float* __restrict__ Uz, const float* __restrict__ Ur,
    const float* __restrict__ Uh, const float* __restrict__ bz,
    const float* __restrict__ br, const float* __restrict__ bh,
    const float* __restrict__ proj,
    float* __restrict__ outCal, float* __restrict__ outHid, int N) {
    const int n = blockIdx.x * 32 + (threadIdx.x >> 3);
    const int b = threadIdx.x & 7;
    if (n >= N) return;

    const size_t io = (size_t)n * 64 + b * 8;
    f2 az[4], ar[4], ah[4];
    const f2* iz2 = (const f2*)(inpZ + io);
    const f2* ir2 = (const f2*)(inpR + io);
    const f2* ih2 = (const f2*)(inpH + io);
#pragma unroll
    for (int k = 0; k < 4; ++k) {
        az[k] = iz2[k];
        ar[k] = ir2[k];
        ah[k] = ih2[k];
    }

    float hv[8];
    {
        const float4* hp = (const float4*)(hidden + (((size_t)(b * N + n)) << 3));
        float4 h0 = hp[0], h1 = hp[1];
        hv[0] = h0.x; hv[1] = h0.y; hv[2] = h0.z; hv[3] = h0.w;
        hv[4] = h1.x; hv[5] = h1.y; hv[6] = h1.z; hv[7] = h1.w;
    }

    const float* uz = Uz + ((size_t)n << 6);
    const float* ur = Ur + ((size_t)n << 6);
    const float* uh = Uh + ((size_t)n << 6);

#pragma unroll
    for (int hh = 0; hh < 8; ++hh) {
        f2 hv2 = {hv[hh], hv[hh]};
        const f2* uzr = (const f2*)(uz + hh * 8);
        const f2* urr = (const f2*)(ur + hh * 8);
#pragma unroll
        for (int k = 0; k < 4; ++k) {
            az[k] = __builtin_elementwise_fma(uzr[k], hv2, az[k]);
            ar[k] = __builtin_elementwise_fma(urr[k], hv2, ar[k]);
        }
    }

    const float* bzp = bz + ((size_t)n << 3);
    const float* brp = br + ((size_t)n << 3);
    float z[8], r[8];
#pragma unroll
    for (int i = 0; i < 8; ++i) {
        float azv = (i & 1) ? az[i >> 1].y : az[i >> 1].x;
        float arv = (i & 1) ? ar[i >> 1].y : ar[i >> 1].x;
        z[i] = fast_sigmoid(azv + bzp[i]);
        r[i] = fast_sigmoid(arv + brp[i]);
    }

#pragma unroll
    for (int hh = 0; hh < 8; ++hh) {
        f2 rh2 = {r[hh] * hv[hh], r[hh] * hv[hh]};
        const f2* uhr = (const f2*)(uh + hh * 8);
#pragma unroll
        for (int k = 0; k < 4; ++k) {
            ah[k] = __builtin_elementwise_fma(uhr[k], rh2, ah[k]);
        }
    }

    const float* bhp = bh + ((size_t)n << 3);
    float hn[8];
    float cv = 0.0f;
#pragma unroll
    for (int i = 0; i < 8; ++i) {
        float ahv = (i & 1) ? ah[i >> 1].y : ah[i >> 1].x;
        float ht = fast_tanh(ahv + bhp[i]);
        hn[i] = (1.0f - z[i]) * hv[i] + z[i] * ht;
        cv += hn[i] * proj[i];
    }

    float4* oh = (float4*)(outHid + (((size_t)(b * N + n)) << 3));
    oh[0] = make_float4(hn[0], hn[1], hn[2], hn[3]);
    oh[1] = make_float4(hn[4], hn[5], hn[6], hn[7]);
    outCal[(size_t)b * N + n] = fmaxf(cv, 0.0f);
}

extern "C" void kernel_launch(void* const* d_in, const int* in_sizes, int n_in,
                              void* d_out, int out_size, void* d_ws, size_t ws_size,
                              hipStream_t stream) {
    const float* calcium = (const float*)d_in[0];
    const float* hidden  = (const float*)d_in[1];
    const int*   src     = (const int*)d_in[2];
    const int*   tgt     = (const int*)d_in[3];
    const float* Wz      = (const float*)d_in[4];
    const float* Wr      = (const float*)d_in[5];
    const float* Wh      = (const float*)d_in[6];
    const float* Uz      = (const float*)d_in[7];
    const float* Ur      = (const float*)d_in[8];
    const float* Uh      = (const float*)d_in[9];
    const float* bz      = (const float*)d_in[10];
    const float* br      = (const float*)d_in[11];
    const float* bh      = (const float*)d_in[12];
    const float* proj    = (const float*)d_in[13];

    const int E = in_sizes[2];
    const int H = in_sizes[13];           // 8
    const int N = in_sizes[10] / H;       // 70000
    (void)n_in; (void)out_size; (void)ws_size;

    float* out = (float*)d_out;
    float* outCal = out;
    float* outHid = out + (size_t)in_sizes[0];

    char* ws = (char*)d_ws;
    float* calT = (float*)ws;                       // N x 8 f32 (2.24 MB)
    float* inp  = (float*)(ws + (4 << 20));         // 3 x N x 64 f32 (53.8 MB)
    float* inpZ = inp;
    float* inpR = inp + (size_t)N * 64;
    float* inpH = inp + (size_t)N * 128;

    // P1: zero accumulators + calT transpose
    {
        int total4 = 3 * N * 16;  // float4 count of inp
        zero_calt<<<2048, 256, 0, stream>>>((float4*)inp, total4, calcium, calT, N);
    }
    // P2: edge scatter via wave-level atomics (4 edges per wave)
    {
        int waves = (E + 3) / 4;
        int blocks = (waves + 3) / 4;  // 4 waves per 256-thread block
        edge_atomic<<<blocks, 256, 0, stream>>>(
            src, tgt, Wz, Wr, Wh, calT, inpZ, inpR, inpH, E);
    }
    // P3: dense GRU
    gru_dense<<<(N + 31) / 32, 256, 0, stream>>>(
        inpZ, inpR, inpH, hidden, Uz, Ur, Uh, bz, br, bh, proj,
        outCal, outHid, N);
}

// Round 20
// 187.241 us; speedup vs baseline: 3.8275x; 3.8275x over previous
//
#include <hip/hip_runtime.h>

// ---------------------------------------------------------------------------
// SparseGRUBrain: N=70000, H=8, E=1.12M, B=8.
// Champion pipeline (R15) + pack_store pos-broadcast:
//   memset(cnt,cursor) -> hist(+calT transpose, rank) -> alloc (block scan +
//   one global atomic per block) -> pack_store (lane-cooperative full-line
//   64B records {Wz,Wr,Wh,cal}; CSR slot computed once per edge, shuffled to
//   the 4 lanes) -> gru_main (one wave per neuron, packed f32x2 math,
//   streaming self-contained records).
// Workspace (bytes):
//   [0,      280K)   cnt
//   [448K,   +4)     cursor
//   [512K,   +560K)  rowCnt (int2 per neuron: {begin, count})
//   [1280K,  +4.5M)  rank
//   [5888K,  +2.3M)  calT ((N+1) x 8 f32)
//   [8320K,  +72M)   recs (E x 64B records)
// ---------------------------------------------------------------------------

typedef float f2 __attribute__((ext_vector_type(2)));

__device__ __forceinline__ float fast_sigmoid(float x) {
    return 1.0f / (1.0f + __expf(-x));
}
__device__ __forceinline__ float fast_tanh(float x) {
    return 2.0f / (1.0f + __expf(-2.0f * x)) - 1.0f;
}

// fp32 -> bf16 bits, round-to-nearest-even
__device__ __forceinline__ unsigned bfr(float x) {
    unsigned u = __float_as_uint(x);
    return (u + 0x7fffu + ((u >> 16) & 1u)) >> 16;
}
__device__ __forceinline__ uint4 pack8(float4 a, float4 b) {
    uint4 r;
    r.x = bfr(a.x) | (bfr(a.y) << 16);
    r.y = bfr(a.z) | (bfr(a.w) << 16);
    r.z = bfr(b.x) | (bfr(b.y) << 16);
    r.w = bfr(b.z) | (bfr(b.w) << 16);
    return r;
}

// unpack 8 bf16 from uint4 into 4 float2 pairs, packed-fma with splatted c2
#define BFMA2(acc, p, c2)                                                      \
    {                                                                          \
        f2 w;                                                                  \
        w.x = __uint_as_float((p).x << 16);                                    \
        w.y = __uint_as_float((p).x & 0xffff0000u);                            \
        acc[0] = __builtin_elementwise_fma(w, c2, acc[0]);                     \
        w.x = __uint_as_float((p).y << 16);                                    \
        w.y = __uint_as_float((p).y & 0xffff0000u);                            \
        acc[1] = __builtin_elementwise_fma(w, c2, acc[1]);                     \
        w.x = __uint_as_float((p).z << 16);                                    \
        w.y = __uint_as_float((p).z & 0xffff0000u);                            \
        acc[2] = __builtin_elementwise_fma(w, c2, acc[2]);                     \
        w.x = __uint_as_float((p).w << 16);                                    \
        w.y = __uint_as_float((p).w & 0xffff0000u);                            \
        acc[3] = __builtin_elementwise_fma(w, c2, acc[3]);                     \
    }

// cnt[t]++ per edge (atomic return = rank within bucket); threads <= N also
// build calT (transpose of calcium, row N zeroed).
__global__ void hist_kernel(const int* __restrict__ tgt, int* __restrict__ cnt,
                            int* __restrict__ rank, const float* __restrict__ cal,
                            float* __restrict__ calT, int N, int E) {
    int i = blockIdx.x * blockDim.x + threadIdx.x;
    if (i <= N) {
        float4* o = (float4*)(calT + (size_t)i * 8);
        if (i == N) {
            o[0] = make_float4(0.f, 0.f, 0.f, 0.f);
            o[1] = make_float4(0.f, 0.f, 0.f, 0.f);
        } else {
            float v[8];
#pragma unroll
            for (int b = 0; b < 8; ++b) v[b] = cal[(size_t)b * N + i];
            o[0] = make_float4(v[0], v[1], v[2], v[3]);
            o[1] = make_float4(v[4], v[5], v[6], v[7]);
        }
    }
    int base = i * 4;
    if (base + 3 < E) {
        int4 t = *(const int4*)(tgt + base);
        int4 r;
        r.x = atomicAdd(&cnt[t.x], 1);
        r.y = atomicAdd(&cnt[t.y], 1);
        r.z = atomicAdd(&cnt[t.z], 1);
        r.w = atomicAdd(&cnt[t.w], 1);
        *(int4*)(rank + base) = r;
    } else {
        for (int k = base; k < E; ++k) rank[k] = atomicAdd(&cnt[tgt[k]], 1);
    }
}

// Row allocation without a global scan: block-local exclusive scan of cnt,
// one atomicAdd(cursor, blockTotal) per block. Writes rowCnt = {begin, count}.
__global__ __launch_bounds__(256) void alloc_kernel(const int* __restrict__ cnt,
                                                    int2* __restrict__ rowCnt,
                                                    int* __restrict__ cursor, int N) {
    __shared__ int waveSum[4];
    const int n = blockIdx.x * 256 + threadIdx.x;
    const int lane = threadIdx.x & 63;
    const int wid = threadIdx.x >> 6;
    int c = (n < N) ? cnt[n] : 0;
    int pre = c;
#pragma unroll
    for (int off = 1; off < 64; off <<= 1) {
        int v = __shfl_up(pre, off, 64);
        if (lane >= off) pre += v;
    }
    if (lane == 63) waveSum[wid] = pre;
    __syncthreads();
    if (threadIdx.x == 0) {
        int s0 = waveSum[0], s1 = waveSum[1], s2 = waveSum[2], s3 = waveSum[3];
        int base = atomicAdd(cursor, s0 + s1 + s2 + s3);
        waveSum[0] = base;
        waveSum[1] = base + s0;
        waveSum[2] = base + s0 + s1;
        waveSum[3] = base + s0 + s1 + s2;
    }
    __syncthreads();
    if (n < N) rowCnt[n] = make_int2(waveSum[wid] + (pre - c), c);
}

// LANE-COOPERATIVE packer: 4 consecutive lanes own one edge. Lane q=0 resolves
// the CSR slot (tgt -> rowCnt -> +rank, done ONCE per edge), broadcast via
// __shfl; lane q packs quarter q of the 64B record (q=0..2: W rows; q=3:
// calT[src]) and stores one uint4 -> each record is one fully-dirty 64B line.
__global__ __launch_bounds__(256) void pack_store(
    const int* __restrict__ src, const int* __restrict__ tgt,
    const int* __restrict__ rank, const int2* __restrict__ rowCnt,
    const float* __restrict__ Wz, const float* __restrict__ Wr,
    const float* __restrict__ Wh, const float* __restrict__ calT,
    uint4* __restrict__ recs, int E) {
    int gid = blockIdx.x * 256 + threadIdx.x;
    int e = gid >> 2;
    int q = gid & 3;
    if (e >= E) return;
    const int lane = threadIdx.x & 63;
    int pos = 0;
    if (q == 0) pos = rowCnt[tgt[e]].x + rank[e];  // once per edge
    pos = __shfl(pos, lane & ~3, 64);              // broadcast to the 4 lanes
    const float* base;
    size_t off;
    if (q == 0)      { base = Wz;   off = (size_t)e * 8; }
    else if (q == 1) { base = Wr;   off = (size_t)e * 8; }
    else if (q == 2) { base = Wh;   off = (size_t)e * 8; }
    else             { base = calT; off = (size_t)src[e] * 8; }
    const float4* p = (const float4*)(base + off);
    float4 a = p[0], b = p[1];
    recs[(size_t)pos * 4 + q] = pack8(a, b);
}

// xor reduce-scatter over the 8 s-lanes: input v[0..7] partials per lane,
// output = fully-reduced value for element index s (lane bits 3,4,5).
__device__ __forceinline__ float rscatter(float v[8], int lane) {
    const bool s0 = (lane & 8) != 0;
    const bool s1 = (lane & 16) != 0;
    const bool s2 = (lane & 32) != 0;
    float w0, w1, w2, w3, x0, x1;
    { float k = s0 ? v[1] : v[0], g = s0 ? v[0] : v[1]; w0 = k + __shfl_xor(g, 8, 64); }
    { float k = s0 ? v[3] : v[2], g = s0 ? v[2] : v[3]; w1 = k + __shfl_xor(g, 8, 64); }
    { float k = s0 ? v[5] : v[4], g = s0 ? v[4] : v[5]; w2 = k + __shfl_xor(g, 8, 64); }
    { float k = s0 ? v[7] : v[6], g = s0 ? v[6] : v[7]; w3 = k + __shfl_xor(g, 8, 64); }
    { float k = s1 ? w1 : w0, g = s1 ? w0 : w1; x0 = k + __shfl_xor(g, 16, 64); }
    { float k = s1 ? w3 : w2, g = s1 ? w2 : w3; x1 = k + __shfl_xor(g, 16, 64); }
    float k = s2 ? x1 : x0, g = s2 ? x0 : x1;
    return k + __shfl_xor(g, 32, 64);
}

// Main: one wave per neuron, 256-thread blocks (4 neurons). lane = s*8 + b.
// Sparse loop streams self-contained 64B records; all math packed f32x2.
// Identical to R15 champion (absmax control: exactly 0.03125).
__global__ __launch_bounds__(256) void gru_main(
    const float* __restrict__ hidden, const uint4* __restrict__ recs,
    const float* __restrict__ Uz, const float* __restrict__ Ur,
    const float* __restrict__ Uh, const float* __restrict__ bz,
    const float* __restrict__ br, const float* __restrict__ bh,
    const float* __restrict__ proj, const int2* __restrict__ rowCnt,
    float* __restrict__ outCal, float* __restrict__ outHid, int N) {
    const int lane = threadIdx.x & 63;
    const int n = blockIdx.x * 4 + (threadIdx.x >> 6);
    if (n >= N) return;
    const int s = lane >> 3;  // slot / h-element index
    const int b = lane & 7;   // batch

    const int2 rc = rowCnt[n];
    const int start = rc.x;
    const int end = rc.x + rc.y;

    // ---- hoisted dense-phase loads (latency hides under the sparse loop) ----
    const size_t hb = ((size_t)(b * N + n)) << 3;
    const float hvS = hidden[hb + s];
    const int ub = (n << 6) + (s << 3);
    const f2* uz2 = (const f2*)(Uz + ub);
    const f2* ur2 = (const f2*)(Ur + ub);
    const f2* uh2 = (const f2*)(Uh + ub);
    f2 uzr[4], urr[4], uhr[4];
#pragma unroll
    for (int k = 0; k < 4; ++k) {
        uzr[k] = uz2[k];
        urr[k] = ur2[k];
        uhr[k] = uh2[k];
    }
    const float bzS = bz[(n << 3) + s];
    const float brS = br[(n << 3) + s];
    const float bhS = bh[(n << 3) + s];
    const float pjS = proj[s];

    f2 az2[4], ar2[4], ah2[4];
#pragma unroll
    for (int k = 0; k < 4; ++k) {
        az2[k] = (f2){0.0f, 0.0f};
        ar2[k] = (f2){0.0f, 0.0f};
        ah2[k] = (f2){0.0f, 0.0f};
    }

    // ---- sparse phase: lane s streams records j = start+s, +8, ... ----
    const unsigned short* recsH = (const unsigned short*)recs;
    for (int j = start + s; j < end; j += 8) {
        const uint4* rp = recs + (size_t)j * 4;
        uint4 pz = rp[0];
        uint4 pr = rp[1];
        uint4 ph = rp[2];
        unsigned cb = recsH[((size_t)j << 5) + 24 + b];
        float c = __uint_as_float(cb << 16);
        f2 c2 = {c, c};
        BFMA2(az2, pz, c2);
        BFMA2(ar2, pr, c2);
        BFMA2(ah2, ph, c2);
    }

    // ---- slot-parallel recurrent partials for h = s (packed) ----
    f2 hv2 = {hvS, hvS};
#pragma unroll
    for (int k = 0; k < 4; ++k) {
        az2[k] = __builtin_elementwise_fma(uzr[k], hv2, az2[k]);
        ar2[k] = __builtin_elementwise_fma(urr[k], hv2, ar2[k]);
    }

    // ---- reduce-scatter -> element-s scalars ----
    float az[8], ar[8];
#pragma unroll
    for (int k = 0; k < 4; ++k) {
        az[2 * k] = az2[k].x; az[2 * k + 1] = az2[k].y;
        ar[2 * k] = ar2[k].x; ar[2 * k + 1] = ar2[k].y;
    }
    float AZ = rscatter(az, lane);
    float AR = rscatter(ar, lane);
    float z = fast_sigmoid(AZ + bzS);
    float r = fast_sigmoid(AR + brS);
    float rhS = r * hvS;

    f2 rh2 = {rhS, rhS};
#pragma unroll
    for (int k = 0; k < 4; ++k) {
        ah2[k] = __builtin_elementwise_fma(uhr[k], rh2, ah2[k]);
    }
    float ah[8];
#pragma unroll
    for (int k = 0; k < 4; ++k) {
        ah[2 * k] = ah2[k].x; ah[2 * k + 1] = ah2[k].y;
    }
    float AH = rscatter(ah, lane);
    float ht = fast_tanh(AH + bhS);
    float hn = (1.0f - z) * hvS + z * ht;

    // ---- projection: butterfly all-reduce over s ----
    float cv = hn * pjS;
    cv += __shfl_xor(cv, 8, 64);
    cv += __shfl_xor(cv, 16, 64);
    cv += __shfl_xor(cv, 32, 64);

    outHid[hb + s] = hn;
    if (s == 0) outCal[b * N + n] = fmaxf(cv, 0.0f);
}

extern "C" void kernel_launch(void* const* d_in, const int* in_sizes, int n_in,
                              void* d_out, int out_size, void* d_ws, size_t ws_size,
                              hipStream_t stream) {
    const float* calcium = (const float*)d_in[0];
    const float* hidden  = (const float*)d_in[1];
    const int*   src     = (const int*)d_in[2];
    const int*   tgt     = (const int*)d_in[3];
    const float* Wz      = (const float*)d_in[4];
    const float* Wr      = (const float*)d_in[5];
    const float* Wh      = (const float*)d_in[6];
    const float* Uz      = (const float*)d_in[7];
    const float* Ur      = (const float*)d_in[8];
    const float* Uh      = (const float*)d_in[9];
    const float* bz      = (const float*)d_in[10];
    const float* br      = (const float*)d_in[11];
    const float* bh      = (const float*)d_in[12];
    const float* proj    = (const float*)d_in[13];

    const int E = in_sizes[2];
    const int H = in_sizes[13];           // 8
    const int N = in_sizes[10] / H;       // 70000
    (void)n_in; (void)out_size; (void)ws_size;

    float* out = (float*)d_out;
    float* outCal = out;
    float* outHid = out + (size_t)in_sizes[0];

    char* ws = (char*)d_ws;
    int*   cnt    = (int*)ws;
    int*   cursor = (int*)(ws + (448 << 10));
    int2*  rowCnt = (int2*)(ws + (512 << 10));
    int*   rank   = (int*)(ws + (1280 << 10));
    float* calT   = (float*)(ws + (5888 << 10));
    uint4* recs   = (uint4*)(ws + (8320 << 10));

    // zero cnt [0,280K) and cursor (at 448K) in one memset
    hipMemsetAsync(ws, 0, (448 << 10) + 4, stream);

    int histThreads = (E + 3) / 4;  // 280000 >= N+1, covers calT duty too
    hist_kernel<<<(histThreads + 255) / 256, 256, 0, stream>>>(
        tgt, cnt, rank, calcium, calT, N, E);
    alloc_kernel<<<(N + 255) / 256, 256, 0, stream>>>(cnt, rowCnt, cursor, N);
    {
        long long pthreads = (long long)E * 4;
        pack_store<<<(int)((pthreads + 255) / 256), 256, 0, stream>>>(
            src, tgt, rank, rowCnt, Wz, Wr, Wh, calT, recs, E);
    }
    gru_main<<<(N + 3) / 4, 256, 0, stream>>>(
        hidden, recs, Uz, Ur, Uh, bz, br, bh, proj,
        rowCnt, outCal, outHid, N);
}

// Round 21
// 181.590 us; speedup vs baseline: 3.9466x; 1.0311x over previous
//
#include <hip/hip_runtime.h>

// ---------------------------------------------------------------------------
// SparseGRUBrain: N=70000, H=8, E=1.12M, B=8.  CHAMPION (R15, 180.7us).
// Pipeline (per call): memset(cnt,cursor) -> hist(+calT transpose, rank) ->
//   alloc (block scan + one global atomic per block) -> pack_store (lane-
//   cooperative full-line 64B records {Wz,Wr,Wh,cal}) -> gru_main (one wave
//   per neuron, packed f32x2 math, streaming self-contained records).
// Evidence ledger (R1-R20): gru 80us latency-equilibrium (8 null levers);
// pack 57us (full-line stores = the one real lever, +35us); fusion 2.5x
// worse (grid.sync); atomic scatter 3.7x worse (840MB RMW write-through).
// Workspace (bytes):
//   [0,      280K)   cnt
//   [448K,   +4)     cursor
//   [512K,   +560K)  rowCnt (int2 per neuron: {begin, count})
//   [1280K,  +4.5M)  rank
//   [5888K,  +2.3M)  calT ((N+1) x 8 f32)
//   [8320K,  +72M)   recs (E x 64B records)
// ---------------------------------------------------------------------------

typedef float f2 __attribute__((ext_vector_type(2)));

__device__ __forceinline__ float fast_sigmoid(float x) {
    return 1.0f / (1.0f + __expf(-x));
}
__device__ __forceinline__ float fast_tanh(float x) {
    return 2.0f / (1.0f + __expf(-2.0f * x)) - 1.0f;
}

// fp32 -> bf16 bits, round-to-nearest-even
__device__ __forceinline__ unsigned bfr(float x) {
    unsigned u = __float_as_uint(x);
    return (u + 0x7fffu + ((u >> 16) & 1u)) >> 16;
}
__device__ __forceinline__ uint4 pack8(float4 a, float4 b) {
    uint4 r;
    r.x = bfr(a.x) | (bfr(a.y) << 16);
    r.y = bfr(a.z) | (bfr(a.w) << 16);
    r.z = bfr(b.x) | (bfr(b.y) << 16);
    r.w = bfr(b.z) | (bfr(b.w) << 16);
    return r;
}

// unpack 8 bf16 from uint4 into 4 float2 pairs, packed-fma with splatted c2
#define BFMA2(acc, p, c2)                                                      \
    {                                                                          \
        f2 w;                                                                  \
        w.x = __uint_as_float((p).x << 16);                                    \
        w.y = __uint_as_float((p).x & 0xffff0000u);                            \
        acc[0] = __builtin_elementwise_fma(w, c2, acc[0]);                     \
        w.x = __uint_as_float((p).y << 16);                                    \
        w.y = __uint_as_float((p).y & 0xffff0000u);                            \
        acc[1] = __builtin_elementwise_fma(w, c2, acc[1]);                     \
        w.x = __uint_as_float((p).z << 16);                                    \
        w.y = __uint_as_float((p).z & 0xffff0000u);                            \
        acc[2] = __builtin_elementwise_fma(w, c2, acc[2]);                     \
        w.x = __uint_as_float((p).w << 16);                                    \
        w.y = __uint_as_float((p).w & 0xffff0000u);                            \
        acc[3] = __builtin_elementwise_fma(w, c2, acc[3]);                     \
    }

// cnt[t]++ per edge (atomic return = rank within bucket); threads <= N also
// build calT (transpose of calcium, row N zeroed).
__global__ void hist_kernel(const int* __restrict__ tgt, int* __restrict__ cnt,
                            int* __restrict__ rank, const float* __restrict__ cal,
                            float* __restrict__ calT, int N, int E) {
    int i = blockIdx.x * blockDim.x + threadIdx.x;
    if (i <= N) {
        float4* o = (float4*)(calT + (size_t)i * 8);
        if (i == N) {
            o[0] = make_float4(0.f, 0.f, 0.f, 0.f);
            o[1] = make_float4(0.f, 0.f, 0.f, 0.f);
        } else {
            float v[8];
#pragma unroll
            for (int b = 0; b < 8; ++b) v[b] = cal[(size_t)b * N + i];
            o[0] = make_float4(v[0], v[1], v[2], v[3]);
            o[1] = make_float4(v[4], v[5], v[6], v[7]);
        }
    }
    int base = i * 4;
    if (base + 3 < E) {
        int4 t = *(const int4*)(tgt + base);
        int4 r;
        r.x = atomicAdd(&cnt[t.x], 1);
        r.y = atomicAdd(&cnt[t.y], 1);
        r.z = atomicAdd(&cnt[t.z], 1);
        r.w = atomicAdd(&cnt[t.w], 1);
        *(int4*)(rank + base) = r;
    } else {
        for (int k = base; k < E; ++k) rank[k] = atomicAdd(&cnt[tgt[k]], 1);
    }
}

// Row allocation without a global scan: block-local exclusive scan of cnt,
// one atomicAdd(cursor, blockTotal) per block. Writes rowCnt = {begin, count}.
__global__ __launch_bounds__(256) void alloc_kernel(const int* __restrict__ cnt,
                                                    int2* __restrict__ rowCnt,
                                                    int* __restrict__ cursor, int N) {
    __shared__ int waveSum[4];
    const int n = blockIdx.x * 256 + threadIdx.x;
    const int lane = threadIdx.x & 63;
    const int wid = threadIdx.x >> 6;
    int c = (n < N) ? cnt[n] : 0;
    int pre = c;
#pragma unroll
    for (int off = 1; off < 64; off <<= 1) {
        int v = __shfl_up(pre, off, 64);
        if (lane >= off) pre += v;
    }
    if (lane == 63) waveSum[wid] = pre;
    __syncthreads();
    if (threadIdx.x == 0) {
        int s0 = waveSum[0], s1 = waveSum[1], s2 = waveSum[2], s3 = waveSum[3];
        int base = atomicAdd(cursor, s0 + s1 + s2 + s3);
        waveSum[0] = base;
        waveSum[1] = base + s0;
        waveSum[2] = base + s0 + s1;
        waveSum[3] = base + s0 + s1 + s2;
    }
    __syncthreads();
    if (n < N) rowCnt[n] = make_int2(waveSum[wid] + (pre - c), c);
}

// LANE-COOPERATIVE packer: 4 consecutive lanes own one edge. Lane q packs
// quarter q of the 64B record (q=0..2: W rows; q=3: calT[src]) and stores one
// uint4 at recs[pos*4+q] -> each record is one fully-dirty 64B line.
__global__ __launch_bounds__(256) void pack_store(
    const int* __restrict__ src, const int* __restrict__ tgt,
    const int* __restrict__ rank, const int2* __restrict__ rowCnt,
    const float* __restrict__ Wz, const float* __restrict__ Wr,
    const float* __restrict__ Wh, const float* __restrict__ calT,
    uint4* __restrict__ recs, int E) {
    int gid = blockIdx.x * 256 + threadIdx.x;
    int e = gid >> 2;
    int q = gid & 3;
    if (e >= E) return;
    int t = tgt[e];                        // broadcast across the 4 lanes
    int pos = rowCnt[t].x + rank[e];
    const float* base;
    size_t off;
    if (q == 0)      { base = Wz;   off = (size_t)e * 8; }
    else if (q == 1) { base = Wr;   off = (size_t)e * 8; }
    else if (q == 2) { base = Wh;   off = (size_t)e * 8; }
    else             { base = calT; off = (size_t)src[e] * 8; }
    const float4* p = (const float4*)(base + off);
    float4 a = p[0], b = p[1];
    recs[(size_t)pos * 4 + q] = pack8(a, b);
}

// xor reduce-scatter over the 8 s-lanes: input v[0..7] partials per lane,
// output = fully-reduced value for element index s (lane bits 3,4,5).
__device__ __forceinline__ float rscatter(float v[8], int lane) {
    const bool s0 = (lane & 8) != 0;
    const bool s1 = (lane & 16) != 0;
    const bool s2 = (lane & 32) != 0;
    float w0, w1, w2, w3, x0, x1;
    { float k = s0 ? v[1] : v[0], g = s0 ? v[0] : v[1]; w0 = k + __shfl_xor(g, 8, 64); }
    { float k = s0 ? v[3] : v[2], g = s0 ? v[2] : v[3]; w1 = k + __shfl_xor(g, 8, 64); }
    { float k = s0 ? v[5] : v[4], g = s0 ? v[4] : v[5]; w2 = k + __shfl_xor(g, 8, 64); }
    { float k = s0 ? v[7] : v[6], g = s0 ? v[6] : v[7]; w3 = k + __shfl_xor(g, 8, 64); }
    { float k = s1 ? w1 : w0, g = s1 ? w0 : w1; x0 = k + __shfl_xor(g, 16, 64); }
    { float k = s1 ? w3 : w2, g = s1 ? w2 : w3; x1 = k + __shfl_xor(g, 16, 64); }
    float k = s2 ? x1 : x0, g = s2 ? x0 : x1;
    return k + __shfl_xor(g, 32, 64);
}

// Main: one wave per neuron, 256-thread blocks (4 neurons). lane = s*8 + b.
// Sparse loop streams self-contained 64B records; all math packed f32x2.
__global__ __launch_bounds__(256) void gru_main(
    const float* __restrict__ hidden, const uint4* __restrict__ recs,
    const float* __restrict__ Uz, const float* __restrict__ Ur,
    const float* __restrict__ Uh, const float* __restrict__ bz,
    const float* __restrict__ br, const float* __restrict__ bh,
    const float* __restrict__ proj, const int2* __restrict__ rowCnt,
    float* __restrict__ outCal, float* __restrict__ outHid, int N) {
    const int lane = threadIdx.x & 63;
    const int n = blockIdx.x * 4 + (threadIdx.x >> 6);
    if (n >= N) return;
    const int s = lane >> 3;  // slot / h-element index
    const int b = lane & 7;   // batch

    const int2 rc = rowCnt[n];
    const int start = rc.x;
    const int end = rc.x + rc.y;

    // ---- hoisted dense-phase loads (latency hides under the sparse loop) ----
    const size_t hb = ((size_t)(b * N + n)) << 3;
    const float hvS = hidden[hb + s];
    const int ub = (n << 6) + (s << 3);
    const f2* uz2 = (const f2*)(Uz + ub);
    const f2* ur2 = (const f2*)(Ur + ub);
    const f2* uh2 = (const f2*)(Uh + ub);
    f2 uzr[4], urr[4], uhr[4];
#pragma unroll
    for (int k = 0; k < 4; ++k) {
        uzr[k] = uz2[k];
        urr[k] = ur2[k];
        uhr[k] = uh2[k];
    }
    const float bzS = bz[(n << 3) + s];
    const float brS = br[(n << 3) + s];
    const float bhS = bh[(n << 3) + s];
    const float pjS = proj[s];

    f2 az2[4], ar2[4], ah2[4];
#pragma unroll
    for (int k = 0; k < 4; ++k) {
        az2[k] = (f2){0.0f, 0.0f};
        ar2[k] = (f2){0.0f, 0.0f};
        ah2[k] = (f2){0.0f, 0.0f};
    }

    // ---- sparse phase: lane s streams records j = start+s, +8, ... ----
    const unsigned short* recsH = (const unsigned short*)recs;
    for (int j = start + s; j < end; j += 8) {
        const uint4* rp = recs + (size_t)j * 4;
        uint4 pz = rp[0];
        uint4 pr = rp[1];
        uint4 ph = rp[2];
        unsigned cb = recsH[((size_t)j << 5) + 24 + b];
        float c = __uint_as_float(cb << 16);
        f2 c2 = {c, c};
        BFMA2(az2, pz, c2);
        BFMA2(ar2, pr, c2);
        BFMA2(ah2, ph, c2);
    }

    // ---- slot-parallel recurrent partials for h = s (packed) ----
    f2 hv2 = {hvS, hvS};
#pragma unroll
    for (int k = 0; k < 4; ++k) {
        az2[k] = __builtin_elementwise_fma(uzr[k], hv2, az2[k]);
        ar2[k] = __builtin_elementwise_fma(urr[k], hv2, ar2[k]);
    }

    // ---- reduce-scatter -> element-s scalars ----
    float az[8], ar[8];
#pragma unroll
    for (int k = 0; k < 4; ++k) {
        az[2 * k] = az2[k].x; az[2 * k + 1] = az2[k].y;
        ar[2 * k] = ar2[k].x; ar[2 * k + 1] = ar2[k].y;
    }
    float AZ = rscatter(az, lane);
    float AR = rscatter(ar, lane);
    float z = fast_sigmoid(AZ + bzS);
    float r = fast_sigmoid(AR + brS);
    float rhS = r * hvS;

    f2 rh2 = {rhS, rhS};
#pragma unroll
    for (int k = 0; k < 4; ++k) {
        ah2[k] = __builtin_elementwise_fma(uhr[k], rh2, ah2[k]);
    }
    float ah[8];
#pragma unroll
    for (int k = 0; k < 4; ++k) {
        ah[2 * k] = ah2[k].x; ah[2 * k + 1] = ah2[k].y;
    }
    float AH = rscatter(ah, lane);
    float ht = fast_tanh(AH + bhS);
    float hn = (1.0f - z) * hvS + z * ht;

    // ---- projection: butterfly all-reduce over s ----
    float cv = hn * pjS;
    cv += __shfl_xor(cv, 8, 64);
    cv += __shfl_xor(cv, 16, 64);
    cv += __shfl_xor(cv, 32, 64);

    outHid[hb + s] = hn;
    if (s == 0) outCal[b * N + n] = fmaxf(cv, 0.0f);
}

extern "C" void kernel_launch(void* const* d_in, const int* in_sizes, int n_in,
                              void* d_out, int out_size, void* d_ws, size_t ws_size,
                              hipStream_t stream) {
    const float* calcium = (const float*)d_in[0];
    const float* hidden  = (const float*)d_in[1];
    const int*   src     = (const int*)d_in[2];
    const int*   tgt     = (const int*)d_in[3];
    const float* Wz      = (const float*)d_in[4];
    const float* Wr      = (const float*)d_in[5];
    const float* Wh      = (const float*)d_in[6];
    const float* Uz      = (const float*)d_in[7];
    const float* Ur      = (const float*)d_in[8];
    const float* Uh      = (const float*)d_in[9];
    const float* bz      = (const float*)d_in[10];
    const float* br      = (const float*)d_in[11];
    const float* bh      = (const float*)d_in[12];
    const float* proj    = (const float*)d_in[13];

    const int E = in_sizes[2];
    const int H = in_sizes[13];           // 8
    const int N = in_sizes[10] / H;       // 70000
    (void)n_in; (void)out_size; (void)ws_size;

    float* out = (float*)d_out;
    float* outCal = out;
    float* outHid = out + (size_t)in_sizes[0];

    char* ws = (char*)d_ws;
    int*   cnt    = (int*)ws;
    int*   cursor = (int*)(ws + (448 << 10));
    int2*  rowCnt = (int2*)(ws + (512 << 10));
    int*   rank   = (int*)(ws + (1280 << 10));
    float* calT   = (float*)(ws + (5888 << 10));
    uint4* recs   = (uint4*)(ws + (8320 << 10));

    // zero cnt [0,280K) and cursor (at 448K) in one memset
    hipMemsetAsync(ws, 0, (448 << 10) + 4, stream);

    int histThreads = (E + 3) / 4;  // 280000 >= N+1, covers calT duty too
    hist_kernel<<<(histThreads + 255) / 256, 256, 0, stream>>>(
        tgt, cnt, rank, calcium, calT, N, E);
    alloc_kernel<<<(N + 255) / 256, 256, 0, stream>>>(cnt, rowCnt, cursor, N);
    {
        long long pthreads = (long long)E * 4;
        pack_store<<<(int)((pthreads + 255) / 256), 256, 0, stream>>>(
            src, tgt, rank, rowCnt, Wz, Wr, Wh, calT, recs, E);
    }
    gru_main<<<(N + 3) / 4, 256, 0, stream>>>(
        hidden, recs, Uz, Ur, Uh, bz, br, bh, proj,
        rowCnt, outCal, outHid, N);
}